// Round 1
// baseline (130.608 us; speedup 1.0000x reference)
//
#include <hip/hip_runtime.h>
#include <math.h>

#define MAX_PIECES 32
#define FT_OUT 512

// One block per batch row. 256 threads; thread t owns columns {2t, 2t+1} of
// both the stm and nstm 512-wide feature-transform accumulators.
__global__ __launch_bounds__(256) void nnue_fwd(
    const int*   __restrict__ stm_idx,   // [2, nnz] flat; feature ids at offset nnz
    const int*   __restrict__ nstm_idx,  // [2, nnz] flat
    const float* __restrict__ values,    // [nnz]
    const float* __restrict__ ft_w,      // [768, 512] row-major
    const float* __restrict__ ft_b,      // [512]
    const float* __restrict__ out_w,     // [1024]
    const float* __restrict__ out_b,     // [1]
    float*       __restrict__ out,       // [B]
    int nnz)
{
    const int b = blockIdx.x;
    const int t = threadIdx.x;

    __shared__ int   s_stm[MAX_PIECES];
    __shared__ int   s_nstm[MAX_PIECES];
    __shared__ float s_val[MAX_PIECES];
    __shared__ float s_red[4];

    // Stage this row's indices + values (batch b owns nnz slots [b*32, b*32+32)).
    if (t < MAX_PIECES) {
        s_stm[t] = stm_idx[nnz + b * MAX_PIECES + t];
    } else if (t < 2 * MAX_PIECES) {
        const int i = t - MAX_PIECES;
        s_nstm[i] = nstm_idx[nnz + b * MAX_PIECES + i];
    } else if (t < 3 * MAX_PIECES) {
        const int i = t - 2 * MAX_PIECES;
        s_val[i] = values[b * MAX_PIECES + i];
    }
    __syncthreads();

    float a0 = 0.f, a1 = 0.f;   // stm accumulator (2 cols)
    float c0 = 0.f, c1 = 0.f;   // nstm accumulator (2 cols)
    const int col = 2 * t;

    #pragma unroll
    for (int i = 0; i < MAX_PIECES; ++i) {
        const float v = s_val[i];
        const float2 w = *(const float2*)(ft_w + s_stm[i]  * FT_OUT + col);
        const float2 u = *(const float2*)(ft_w + s_nstm[i] * FT_OUT + col);
        a0 = fmaf(w.x, v, a0);
        a1 = fmaf(w.y, v, a1);
        c0 = fmaf(u.x, v, c0);
        c1 = fmaf(u.y, v, c1);
    }

    // bias + clip(0,1)
    const float2 fb = *(const float2*)(ft_b + col);
    a0 = fminf(fmaxf(a0 + fb.x, 0.f), 1.f);
    a1 = fminf(fmaxf(a1 + fb.y, 0.f), 1.f);
    c0 = fminf(fmaxf(c0 + fb.x, 0.f), 1.f);
    c1 = fminf(fmaxf(c1 + fb.y, 0.f), 1.f);

    // head: hidden . out_w   (stm cols map to [0,512), nstm to [512,1024))
    const float2 w0 = *(const float2*)(out_w + col);
    const float2 w1 = *(const float2*)(out_w + FT_OUT + col);
    float p = a0 * w0.x + a1 * w0.y + c0 * w1.x + c1 * w1.y;

    // wave (64-lane) shuffle reduce, then cross-wave via LDS
    #pragma unroll
    for (int off = 32; off > 0; off >>= 1)
        p += __shfl_down(p, off, 64);
    const int wave = t >> 6;
    const int lane = t & 63;
    if (lane == 0) s_red[wave] = p;
    __syncthreads();
    if (t == 0) {
        const float s = s_red[0] + s_red[1] + s_red[2] + s_red[3] + out_b[0];
        out[b] = 1.f / (1.f + expf(-s));
    }
}

extern "C" void kernel_launch(void* const* d_in, const int* in_sizes, int n_in,
                              void* d_out, int out_size, void* d_ws, size_t ws_size,
                              hipStream_t stream) {
    const int*   stm_idx  = (const int*)d_in[0];
    const int*   nstm_idx = (const int*)d_in[1];
    const float* values   = (const float*)d_in[2];
    const float* ft_w     = (const float*)d_in[3];
    const float* ft_b     = (const float*)d_in[4];
    const float* out_w    = (const float*)d_in[5];
    const float* out_b    = (const float*)d_in[6];
    float*       out      = (float*)d_out;

    const int nnz = in_sizes[0] / 2;   // stm_indices is [2, nnz]
    const int B   = out_size;          // [B, 1] output

    nnue_fwd<<<B, 256, 0, stream>>>(stm_idx, nstm_idx, values, ft_w, ft_b,
                                    out_w, out_b, out, nnz);
}

// Round 2
// 90.957 us; speedup vs baseline: 1.4359x; 1.4359x over previous
//
#include <hip/hip_runtime.h>
#include <math.h>

#define MAX_PIECES 32
#define FT_OUT 512
#define N_FEATURES 768

// ---------------------------------------------------------------------------
// Pass 1: convert ft_w (768x512 fp32) -> bf16 table in d_ws (RNE rounding).
// ---------------------------------------------------------------------------
__global__ __launch_bounds__(256) void cvt_bf16(
    const float* __restrict__ ft_w, unsigned short* __restrict__ wtab, int n)
{
    const int i = (blockIdx.x * 256 + threadIdx.x) * 4;
    if (i >= n) return;
    const float4 f = *(const float4*)(ft_w + i);
    ushort4 o;
    const float vf[4] = {f.x, f.y, f.z, f.w};
    unsigned short ov[4];
    #pragma unroll
    for (int j = 0; j < 4; ++j) {
        unsigned int u = __float_as_uint(vf[j]);
        u += 0x7fffu + ((u >> 16) & 1u);          // round-to-nearest-even
        ov[j] = (unsigned short)(u >> 16);
    }
    o.x = ov[0]; o.y = ov[1]; o.z = ov[2]; o.w = ov[3];
    *(ushort4*)(wtab + i) = o;
}

// ---------------------------------------------------------------------------
// Pass 2: gather-accumulate + head.
// Block = 256 threads = 4 waves; handles 2 batch rows.
//   wave g: rb = g>>1 (row within block), side = g&1 (0=stm, 1=nstm)
//   lane owns 8 columns [lane*8, lane*8+8); one wave load (16B/lane) covers a
//   full 512-col bf16 feature row (1024 B) in a single coalesced instruction.
// ---------------------------------------------------------------------------
__global__ __launch_bounds__(256) void nnue_fwd(
    const int*   __restrict__ stm_idx,   // [2, nnz] flat; feature ids at +nnz
    const int*   __restrict__ nstm_idx,
    const float* __restrict__ values,    // [nnz]
    const unsigned short* __restrict__ wtab, // [768, 512] bf16
    const float* __restrict__ ft_b,      // [512]
    const float* __restrict__ out_w,     // [1024]
    const float* __restrict__ out_b,     // [1]
    float*       __restrict__ out,       // [B]
    int nnz)
{
    const int t    = threadIdx.x;
    const int g    = t >> 6;        // wave id 0..3
    const int lane = t & 63;
    const int rb   = g >> 1;        // row within block
    const int side = g & 1;         // 0 = stm, 1 = nstm
    const int row  = blockIdx.x * 2 + rb;

    __shared__ int   s_idx[4][MAX_PIECES];   // [g][piece]
    __shared__ float s_val[2][MAX_PIECES];   // [rb][piece]
    __shared__ float s_red[4];

    if (t < 128) {
        const int lg = t >> 5, li = t & 31;
        const int lrow = blockIdx.x * 2 + (lg >> 1);
        const int* src = (lg & 1) ? nstm_idx : stm_idx;
        s_idx[lg][li] = src[nnz + lrow * MAX_PIECES + li];
    } else if (t < 192) {
        const int lrb = (t >> 5) & 1, li = t & 31;
        const int lrow = blockIdx.x * 2 + lrb;
        s_val[lrb][li] = values[lrow * MAX_PIECES + li];
    }
    __syncthreads();

    float acc[8];
    #pragma unroll
    for (int j = 0; j < 8; ++j) acc[j] = 0.f;

    const int colbase = lane * 8;

    #pragma unroll
    for (int i = 0; i < MAX_PIECES; ++i) {
        const int   feat = s_idx[g][i];
        const float v    = s_val[rb][i];
        const uint4 u = *(const uint4*)(wtab + feat * FT_OUT + colbase);
        const unsigned int uw[4] = {u.x, u.y, u.z, u.w};
        #pragma unroll
        for (int k = 0; k < 4; ++k) {
            const float lo = __uint_as_float(uw[k] << 16);
            const float hi = __uint_as_float(uw[k] & 0xffff0000u);
            acc[2 * k]     = fmaf(lo, v, acc[2 * k]);
            acc[2 * k + 1] = fmaf(hi, v, acc[2 * k + 1]);
        }
    }

    // bias + clip(0,1), then partial dot with head weights
    const float4 b0 = *(const float4*)(ft_b + colbase);
    const float4 b1 = *(const float4*)(ft_b + colbase + 4);
    const float bb[8] = {b0.x, b0.y, b0.z, b0.w, b1.x, b1.y, b1.z, b1.w};
    const float4 w0 = *(const float4*)(out_w + side * FT_OUT + colbase);
    const float4 w1 = *(const float4*)(out_w + side * FT_OUT + colbase + 4);
    const float ww[8] = {w0.x, w0.y, w0.z, w0.w, w1.x, w1.y, w1.z, w1.w};

    float p = 0.f;
    #pragma unroll
    for (int j = 0; j < 8; ++j) {
        const float h = fminf(fmaxf(acc[j] + bb[j], 0.f), 1.f);
        p = fmaf(h, ww[j], p);
    }

    // 64-lane shuffle reduce -> one partial per wave
    #pragma unroll
    for (int off = 32; off > 0; off >>= 1)
        p += __shfl_down(p, off, 64);
    if (lane == 0) s_red[g] = p;
    __syncthreads();

    if (t < 2) {
        const float s = s_red[2 * t] + s_red[2 * t + 1] + out_b[0];
        out[blockIdx.x * 2 + t] = 1.f / (1.f + expf(-s));
    }
}

extern "C" void kernel_launch(void* const* d_in, const int* in_sizes, int n_in,
                              void* d_out, int out_size, void* d_ws, size_t ws_size,
                              hipStream_t stream) {
    const int*   stm_idx  = (const int*)d_in[0];
    const int*   nstm_idx = (const int*)d_in[1];
    const float* values   = (const float*)d_in[2];
    const float* ft_w     = (const float*)d_in[3];
    const float* ft_b     = (const float*)d_in[4];
    const float* out_w    = (const float*)d_in[5];
    const float* out_b    = (const float*)d_in[6];
    float*       out      = (float*)d_out;

    const int nnz = in_sizes[0] / 2;        // stm_indices is [2, nnz]
    const int B   = out_size;               // [B, 1]
    const int nw  = N_FEATURES * FT_OUT;    // 393216

    unsigned short* wtab = (unsigned short*)d_ws;

    cvt_bf16<<<(nw / 4 + 255) / 256, 256, 0, stream>>>(ft_w, wtab, nw);
    nnue_fwd<<<B / 2, 256, 0, stream>>>(stm_idx, nstm_idx, values, wtab,
                                        ft_b, out_w, out_b, out, nnz);
}